// Round 5
// baseline (435.021 us; speedup 1.0000x reference)
//
#include <hip/hip_runtime.h>
#include <hip/hip_bf16.h>
#include <stdint.h>

#define N_NODES 100000
#define N_EDGES 1600000
#define NB_P 400      // partition blocks
#define EPP 4000      // edges per partition block (400*4000 = 1.6M)
#define NBUCK 391     // ceil(100000/256) buckets of 256 dst nodes

typedef __bf16 bf16x8 __attribute__((ext_vector_type(8)));
typedef float f32x4 __attribute__((ext_vector_type(4)));
typedef unsigned short u16;

__device__ __forceinline__ u16 f2b(float f) {
    uint32_t u = __builtin_bit_cast(uint32_t, f);
    uint32_t r = (u + 0x7fffu + ((u >> 16) & 1u)) >> 16;
    return (u16)r;
}
__device__ __forceinline__ float blo(uint32_t p) {   // low bf16 -> f32
    return __builtin_bit_cast(float, p << 16);
}
__device__ __forceinline__ float bhi(uint32_t p) {   // high bf16 -> f32 (one AND)
    return __builtin_bit_cast(float, p & 0xffff0000u);
}

// ---- A: per-(bucket,block) histogram, LDS atomics only ----
__global__ __launch_bounds__(256) void part_hist(const int* __restrict__ dstp,
                                                 int* __restrict__ hist) {
    __shared__ int h[NBUCK];
    int t = threadIdx.x, p = blockIdx.x;
    for (int b = t; b < NBUCK; b += 256) h[b] = 0;
    __syncthreads();
    int e0 = p * EPP;
    for (int i = t; i < EPP; i += 256)
        atomicAdd(&h[dstp[e0 + i] >> 8], 1);
    __syncthreads();
    for (int b = t; b < NBUCK; b += 256) hist[b * NB_P + p] = h[b];
}

// ---- B1: per-bucket totals (one wave per bucket) ----
__global__ void bucket_totals(const int* __restrict__ hist, int* __restrict__ totals) {
    int w = (blockIdx.x * 256 + threadIdx.x) >> 6;
    if (w >= NBUCK) return;
    int lane = threadIdx.x & 63;
    int s = 0;
    for (int p = lane; p < NB_P; p += 64) s += hist[w * NB_P + p];
    #pragma unroll
    for (int off = 32; off; off >>= 1) s += __shfl_down(s, off, 64);
    if (lane == 0) totals[w] = s;
}

// ---- B2: exclusive scan of bucket totals -> base (single wave) ----
__global__ void bucket_scan(const int* __restrict__ totals, int* __restrict__ base,
                            int* __restrict__ rowptr) {
    int lane = threadIdx.x;  // 64 threads
    int carry = 0;
    for (int s0 = 0; s0 < NBUCK; s0 += 64) {
        int b = s0 + lane;
        int v = (b < NBUCK) ? totals[b] : 0;
        int x = v;
        #pragma unroll
        for (int off = 1; off < 64; off <<= 1) {
            int y = __shfl_up(x, off, 64);
            if (lane >= off) x += y;
        }
        if (b < NBUCK) base[b] = carry + x - v;
        carry += __shfl(x, 63, 64);
    }
    if (lane == 0) { base[NBUCK] = carry; rowptr[N_NODES] = carry; }
}

// ---- B3: per-bucket exclusive scan across partition blocks -> off ----
__global__ void bucket_off(const int* __restrict__ hist, const int* __restrict__ base,
                           int* __restrict__ off) {
    int w = (blockIdx.x * 256 + threadIdx.x) >> 6;
    if (w >= NBUCK) return;
    int lane = threadIdx.x & 63;
    int run = base[w];
    for (int s0 = 0; s0 < NB_P; s0 += 64) {
        int p = s0 + lane;
        int v = (p < NB_P) ? hist[w * NB_P + p] : 0;
        int x = v;
        #pragma unroll
        for (int o = 1; o < 64; o <<= 1) {
            int y = __shfl_up(x, o, 64);
            if (lane >= o) x += y;
        }
        if (p < NB_P) off[w * NB_P + p] = run + x - v;
        run += __shfl(x, 63, 64);
    }
}

// ---- C: partition scatter via LDS cursors (no global atomics) ----
__global__ __launch_bounds__(256) void part_scatter(const int* __restrict__ srcp,
                                                    const int* __restrict__ dstp,
                                                    const float* __restrict__ ew,
                                                    const int* __restrict__ off,
                                                    int4* __restrict__ part) {
    __shared__ int cur[NBUCK];
    int t = threadIdx.x, p = blockIdx.x;
    for (int b = t; b < NBUCK; b += 256) cur[b] = off[b * NB_P + p];
    __syncthreads();
    int e0 = p * EPP;
    for (int i = t; i < EPP; i += 256) {
        int e = e0 + i;
        int s = srcp[e], d = dstp[e];
        float w = ew[e];
        int pos = atomicAdd(&cur[d >> 8], 1);
        int4 E;
        E.x = s; E.y = d; E.z = __float_as_int(w); E.w = 0;
        part[pos] = E;
    }
}

// ---- D: per-bucket CSR build + rowptr + dinv ----
__global__ __launch_bounds__(256) void bucket_build(const int4* __restrict__ part,
                                                    const int* __restrict__ base,
                                                    int* __restrict__ rowptr,
                                                    float* __restrict__ dinv,
                                                    int2* __restrict__ csr) {
    __shared__ int h[256];
    __shared__ float dw[256];
    __shared__ int cur[256];
    __shared__ int wsum[4];
    int t = threadIdx.x, b = blockIdx.x;
    h[t] = 0; dw[t] = 0.f;
    __syncthreads();
    int jb = base[b], je = base[b + 1];
    for (int i = jb + t; i < je; i += 256) {
        int4 E = part[i];
        int li = E.y & 255;
        atomicAdd(&h[li], 1);
        atomicAdd(&dw[li], __int_as_float(E.z));
    }
    __syncthreads();
    int lane = t & 63, wid = t >> 6;
    int v = h[t];
    int x = v;
    #pragma unroll
    for (int o = 1; o < 64; o <<= 1) {
        int y = __shfl_up(x, o, 64);
        if (lane >= o) x += y;
    }
    if (lane == 63) wsum[wid] = x;
    __syncthreads();
    int woff = 0;
    for (int j = 0; j < wid; j++) woff += wsum[j];
    int excl = jb + woff + x - v;
    int node = b * 256 + t;
    if (node < N_NODES) {
        rowptr[node] = excl;
        float s = dw[t];
        dinv[node] = (s > 0.f) ? rsqrtf(fmaxf(s, 1e-30f)) : 0.f;
    }
    cur[t] = excl;
    __syncthreads();
    for (int i = jb + t; i < je; i += 256) {
        int4 E = part[i];
        int li = E.y & 255;
        int pos = atomicAdd(&cur[li], 1);
        int2 c;
        c.x = E.x; c.y = E.z;
        csr[pos] = c;
    }
}

// ---- all three weights: fp32 [K x Dout] -> bf16 [Dout x K] transposed ----
__global__ void wconv_all(const float* __restrict__ W1, const float* __restrict__ W2,
                          const float* __restrict__ W3, u16* __restrict__ Wt1,
                          u16* __restrict__ Wt2, u16* __restrict__ Wt3) {
    int i = blockIdx.x * 256 + threadIdx.x;
    if (i < 16384) {                       // W1: 128x128
        int k = i >> 7, n = i & 127;
        Wt1[n * 128 + k] = f2b(W1[i]);
    } else if (i < 32768) {                // W2: 128x128
        int j = i - 16384;
        int k = j >> 7, n = j & 127;
        Wt2[n * 128 + k] = f2b(W2[j]);
    } else if (i < 40960) {                // W3: 128x64
        int j = i - 32768;
        int k = j >> 6, n = j & 63;
        Wt3[n * 128 + k] = f2b(W3[j]);
    }
}

// ---- GEMM layer1: A fp32 [N x 128] @ W -> bf16 C scaled by dinv[row] ----
__global__ __launch_bounds__(256) void gemm_f32A(const float* __restrict__ A,
                                                 const u16* __restrict__ Bt,
                                                 const float* __restrict__ dinv,
                                                 u16* __restrict__ C, int Dout) {
    int wid = (blockIdx.x * 256 + threadIdx.x) >> 6;
    if (wid >= N_NODES / 16) return;
    int lane = threadIdx.x & 63;
    int m = lane & 15;
    int k0 = (lane >> 4) * 8;
    int r0 = wid * 16;
    const float* ap = A + (size_t)(r0 + m) * 128 + k0;
    bf16x8 a[4];
    #pragma unroll
    for (int q = 0; q < 4; q++) {
        float4 lo = *(const float4*)(ap + q * 32);
        float4 hi = *(const float4*)(ap + q * 32 + 4);
        union { u16 s[8]; bf16x8 v; } u_;
        u_.s[0] = f2b(lo.x); u_.s[1] = f2b(lo.y); u_.s[2] = f2b(lo.z); u_.s[3] = f2b(lo.w);
        u_.s[4] = f2b(hi.x); u_.s[5] = f2b(hi.y); u_.s[6] = f2b(hi.z); u_.s[7] = f2b(hi.w);
        a[q] = u_.v;
    }
    int ntiles = Dout >> 4;
    int rbase = r0 + ((lane >> 4) << 2);
    float dv[4];
    #pragma unroll
    for (int i2 = 0; i2 < 4; i2++) dv[i2] = dinv[rbase + i2];
    for (int tn = 0; tn < ntiles; tn++) {
        const u16* bp = Bt + (size_t)(tn * 16 + m) * 128 + k0;
        f32x4 acc = {0.f, 0.f, 0.f, 0.f};
        acc = __builtin_amdgcn_mfma_f32_16x16x32_bf16(a[0], *(const bf16x8*)(bp + 0),  acc, 0, 0, 0);
        acc = __builtin_amdgcn_mfma_f32_16x16x32_bf16(a[1], *(const bf16x8*)(bp + 32), acc, 0, 0, 0);
        acc = __builtin_amdgcn_mfma_f32_16x16x32_bf16(a[2], *(const bf16x8*)(bp + 64), acc, 0, 0, 0);
        acc = __builtin_amdgcn_mfma_f32_16x16x32_bf16(a[3], *(const bf16x8*)(bp + 96), acc, 0, 0, 0);
        int col = tn * 16 + m;
        #pragma unroll
        for (int i2 = 0; i2 < 4; i2++)
            C[(size_t)(rbase + i2) * Dout + col] = f2b(acc[i2] * dv[i2]);
    }
}

// ---- GEMM layers 2/3: A bf16 [N x 128] @ W -> bf16 C scaled by dinv[row] ----
__global__ __launch_bounds__(256) void gemm_bf16(const u16* __restrict__ A,
                                                 const u16* __restrict__ Bt,
                                                 const float* __restrict__ dinv,
                                                 u16* __restrict__ C, int Dout) {
    int wid = (blockIdx.x * 256 + threadIdx.x) >> 6;
    if (wid >= N_NODES / 16) return;
    int lane = threadIdx.x & 63;
    int m = lane & 15;
    int k0 = (lane >> 4) * 8;
    int r0 = wid * 16;
    const u16* ap = A + (size_t)(r0 + m) * 128 + k0;
    bf16x8 a0 = *(const bf16x8*)(ap + 0);
    bf16x8 a1 = *(const bf16x8*)(ap + 32);
    bf16x8 a2 = *(const bf16x8*)(ap + 64);
    bf16x8 a3 = *(const bf16x8*)(ap + 96);
    int ntiles = Dout >> 4;
    int rbase = r0 + ((lane >> 4) << 2);
    float dv[4];
    #pragma unroll
    for (int i2 = 0; i2 < 4; i2++) dv[i2] = dinv[rbase + i2];
    for (int tn = 0; tn < ntiles; tn++) {
        const u16* bp = Bt + (size_t)(tn * 16 + m) * 128 + k0;
        f32x4 acc = {0.f, 0.f, 0.f, 0.f};
        acc = __builtin_amdgcn_mfma_f32_16x16x32_bf16(a0, *(const bf16x8*)(bp + 0),  acc, 0, 0, 0);
        acc = __builtin_amdgcn_mfma_f32_16x16x32_bf16(a1, *(const bf16x8*)(bp + 32), acc, 0, 0, 0);
        acc = __builtin_amdgcn_mfma_f32_16x16x32_bf16(a2, *(const bf16x8*)(bp + 64), acc, 0, 0, 0);
        acc = __builtin_amdgcn_mfma_f32_16x16x32_bf16(a3, *(const bf16x8*)(bp + 96), acc, 0, 0, 0);
        int col = tn * 16 + m;
        #pragma unroll
        for (int i2 = 0; i2 < 4; i2++)
            C[(size_t)(rbase + i2) * Dout + col] = f2b(acc[i2] * dv[i2]);
    }
}

// ---- aggregation dim=128: one wave/node, 16 lanes/edge, dwordx4 gathers,
//      4 edges per wave-load, wave-private LDS meta (no shfl, no guards) ----
__global__ __launch_bounds__(256) void agg128(const u16* __restrict__ H,
                                              const int* __restrict__ row_ptr,
                                              const int2* __restrict__ csr,
                                              const float* __restrict__ dinv,
                                              const float* __restrict__ bias,
                                              u16* __restrict__ out, int do_relu) {
    __shared__ int2 ms_all[4][64];
    int wslot = threadIdx.x >> 6;
    int node = blockIdx.x * 4 + wslot;
    if (node >= N_NODES) return;
    int lane = threadIdx.x & 63;
    int grp = lane >> 4;        // edge sub-slot 0..3
    int li = lane & 15;         // lane within edge (8 cols each)
    int2* ms = ms_all[wslot];
    float4 bia = *(const float4*)(bias + 8 * li);
    float4 bib = *(const float4*)(bias + 8 * li + 4);
    float acc[8] = {0.f, 0.f, 0.f, 0.f, 0.f, 0.f, 0.f, 0.f};
    int jb = row_ptr[node], je = row_ptr[node + 1];
    for (int base = jb; base < je; base += 64) {
        int n = je - base;
        if (n > 64) n = 64;
        int2 m;
        if (base + lane < je) m = csr[base + lane];
        else { m.x = 0; m.y = 0; }          // w=0 padding: guard-free inner loop
        ms[lane] = m;
        for (int e = 0; e < n; e += 16) {
            uint4 p[4]; float w[4];
            #pragma unroll
            for (int q = 0; q < 4; q++) {
                int2 mm = ms[(e + q * 4 + grp) & 63];
                w[q] = __int_as_float(mm.y);
                p[q] = *(const uint4*)(H + (size_t)mm.x * 128 + li * 8);
            }
            #pragma unroll
            for (int q = 0; q < 4; q++) {
                acc[0] += w[q] * blo(p[q].x); acc[1] += w[q] * bhi(p[q].x);
                acc[2] += w[q] * blo(p[q].y); acc[3] += w[q] * bhi(p[q].y);
                acc[4] += w[q] * blo(p[q].z); acc[5] += w[q] * bhi(p[q].z);
                acc[6] += w[q] * blo(p[q].w); acc[7] += w[q] * bhi(p[q].w);
            }
        }
    }
    #pragma unroll
    for (int d = 0; d < 8; d++) {
        acc[d] += __shfl_xor(acc[d], 16, 64);
        acc[d] += __shfl_xor(acc[d], 32, 64);
    }
    if (lane < 16) {
        float dv = dinv[node];
        float r[8];
        r[0] = fmaf(dv, acc[0], bia.x); r[1] = fmaf(dv, acc[1], bia.y);
        r[2] = fmaf(dv, acc[2], bia.z); r[3] = fmaf(dv, acc[3], bia.w);
        r[4] = fmaf(dv, acc[4], bib.x); r[5] = fmaf(dv, acc[5], bib.y);
        r[6] = fmaf(dv, acc[6], bib.z); r[7] = fmaf(dv, acc[7], bib.w);
        if (do_relu) {
            #pragma unroll
            for (int d = 0; d < 8; d++) r[d] = fmaxf(r[d], 0.f);
        }
        uint4 st;
        st.x = (uint32_t)f2b(r[0]) | ((uint32_t)f2b(r[1]) << 16);
        st.y = (uint32_t)f2b(r[2]) | ((uint32_t)f2b(r[3]) << 16);
        st.z = (uint32_t)f2b(r[4]) | ((uint32_t)f2b(r[5]) << 16);
        st.w = (uint32_t)f2b(r[6]) | ((uint32_t)f2b(r[7]) << 16);
        *(uint4*)(out + (size_t)node * 128 + li * 8) = st;
    }
}

// ---- final aggregation dim=64: 16 lanes/edge, dwordx2 gathers, fp32 out x2 ----
__global__ __launch_bounds__(256) void agg64_out(const u16* __restrict__ H,
                                                 const int* __restrict__ row_ptr,
                                                 const int2* __restrict__ csr,
                                                 const float* __restrict__ dinv,
                                                 const float* __restrict__ bias,
                                                 float* __restrict__ out) {
    __shared__ int2 ms_all[4][64];
    int wslot = threadIdx.x >> 6;
    int node = blockIdx.x * 4 + wslot;
    if (node >= N_NODES) return;
    int lane = threadIdx.x & 63;
    int grp = lane >> 4;
    int li = lane & 15;         // 4 cols each
    int2* ms = ms_all[wslot];
    float4 bi = *(const float4*)(bias + 4 * li);
    float acc[4] = {0.f, 0.f, 0.f, 0.f};
    int jb = row_ptr[node], je = row_ptr[node + 1];
    for (int base = jb; base < je; base += 64) {
        int n = je - base;
        if (n > 64) n = 64;
        int2 m;
        if (base + lane < je) m = csr[base + lane];
        else { m.x = 0; m.y = 0; }
        ms[lane] = m;
        for (int e = 0; e < n; e += 16) {
            uint2 p[4]; float w[4];
            #pragma unroll
            for (int q = 0; q < 4; q++) {
                int2 mm = ms[(e + q * 4 + grp) & 63];
                w[q] = __int_as_float(mm.y);
                p[q] = *(const uint2*)(H + (size_t)mm.x * 64 + li * 4);
            }
            #pragma unroll
            for (int q = 0; q < 4; q++) {
                acc[0] += w[q] * blo(p[q].x); acc[1] += w[q] * bhi(p[q].x);
                acc[2] += w[q] * blo(p[q].y); acc[3] += w[q] * bhi(p[q].y);
            }
        }
    }
    #pragma unroll
    for (int d = 0; d < 4; d++) {
        acc[d] += __shfl_xor(acc[d], 16, 64);
        acc[d] += __shfl_xor(acc[d], 32, 64);
    }
    if (lane < 16) {
        float dv = dinv[node];
        float4 r;
        r.x = fmaf(dv, acc[0], bi.x);
        r.y = fmaf(dv, acc[1], bi.y);
        r.z = fmaf(dv, acc[2], bi.z);
        r.w = fmaf(dv, acc[3], bi.w);
        size_t o = (size_t)node * 64 + li * 4;
        *(float4*)(out + o) = r;
        *(float4*)(out + (size_t)N_NODES * 64 + o) = r;
    }
}

extern "C" void kernel_launch(void* const* d_in, const int* in_sizes, int n_in,
                              void* d_out, int out_size, void* d_ws, size_t ws_size,
                              hipStream_t stream) {
    const float* x  = (const float*)d_in[0];
    const int* eidx = (const int*)d_in[1];
    const float* ew = (const float*)d_in[2];
    const float* W1 = (const float*)d_in[3];
    const float* b1 = (const float*)d_in[4];
    const float* W2 = (const float*)d_in[5];
    const float* b2 = (const float*)d_in[6];
    const float* W3 = (const float*)d_in[7];
    const float* b3 = (const float*)d_in[8];
    const int* srcp = eidx;
    const int* dstp = eidx + N_EDGES;

    char* ws = (char*)d_ws;
    size_t off_ = 0;
    auto alloc = [&](size_t bytes) -> void* {
        void* p = ws + off_;
        off_ += (bytes + 255) & ~(size_t)255;
        return p;
    };
    int*   hist   = (int*)  alloc((size_t)NBUCK * NB_P * 4);
    int*   offm   = (int*)  alloc((size_t)NBUCK * NB_P * 4);
    int*   totals = (int*)  alloc((size_t)NBUCK * 4);
    int*   base   = (int*)  alloc((size_t)(NBUCK + 1) * 4);
    int*   rowptr = (int*)  alloc((size_t)(N_NODES + 1) * 4);
    int2*  csr    = (int2*) alloc((size_t)N_EDGES * 8);
    float* dinv   = (float*)alloc((size_t)N_NODES * 4);
    u16*   Wt1    = (u16*)  alloc(128 * 128 * 2);
    u16*   Wt2    = (u16*)  alloc(128 * 128 * 2);
    u16*   Wt3    = (u16*)  alloc(128 * 64 * 2);
    u16*   bufA   = (u16*)  alloc((size_t)N_NODES * 128 * 2);
    u16*   bufB   = (u16*)  alloc((size_t)N_NODES * 128 * 2);
    // part aliases bufA: consumed by bucket_build before gemm1 writes bufA.
    int4*  part   = (int4*)bufA;   // 1.6M * 16B = 25.6MB == bufA size

    part_hist<<<NB_P, 256, 0, stream>>>(dstp, hist);
    bucket_totals<<<(NBUCK + 3) / 4, 256, 0, stream>>>(hist, totals);
    bucket_scan<<<1, 64, 0, stream>>>(totals, base, rowptr);
    bucket_off<<<(NBUCK + 3) / 4, 256, 0, stream>>>(hist, base, offm);
    part_scatter<<<NB_P, 256, 0, stream>>>(srcp, dstp, ew, offm, part);
    bucket_build<<<NBUCK, 256, 0, stream>>>(part, base, rowptr, dinv, csr);
    wconv_all<<<160, 256, 0, stream>>>(W1, W2, W3, Wt1, Wt2, Wt3);

    int gemm_blocks = (N_NODES / 16 + 3) / 4;  // 4 waves/block
    gemm_f32A<<<gemm_blocks, 256, 0, stream>>>(x, Wt1, dinv, bufA, 128);
    agg128<<<N_NODES / 4, 256, 0, stream>>>(bufA, rowptr, csr, dinv, b1, bufB, 1);
    gemm_bf16<<<gemm_blocks, 256, 0, stream>>>(bufB, Wt2, dinv, bufA, 128);
    agg128<<<N_NODES / 4, 256, 0, stream>>>(bufA, rowptr, csr, dinv, b2, bufB, 1);
    gemm_bf16<<<gemm_blocks, 256, 0, stream>>>(bufB, Wt3, dinv, bufA, 64);
    agg64_out<<<N_NODES / 4, 256, 0, stream>>>(bufA, rowptr, csr, dinv, b3, (float*)d_out);
}